// Round 7
// baseline (1062.095 us; speedup 1.0000x reference)
//
#include <hip/hip_runtime.h>

// Problem constants (from reference)
#define NPTS 32768
#define DIM  64
#define NCLS 50
#define NH   5
#define NW1  6            // windows + frame
#define NBOX (NH * NW1)   // 30 boxes per class
#define HALF (NPTS / 2)   // 2 points per thread

// d_out layout: [ data: NPTS*DIM ][ contains: NCLS*NPTS ][ dists: NCLS*NH*NW1*NPTS ]
#define DATA_ELEMS   (NPTS * DIM)
#define CONT_ELEMS   (NCLS * NPTS)
#define DIST_OFFSET  (DATA_ELEMS + CONT_ELEMS)

typedef _Float16 h2 __attribute__((ext_vector_type(2)));
typedef _Float16 h8 __attribute__((ext_vector_type(8)));  // 16 B = one ds_read_b128

// Pass-through copy of `data`.
__global__ __launch_bounds__(256) void copy_k(const float4* __restrict__ in,
                                              float4* __restrict__ out) {
    const int i = blockIdx.x * 256 + threadIdx.x;
    out[i] = in[i];
}

// prep_k: sort corners to lo/hi, convert to packed f16 pairs, box-major:
// per box (c,b): 64 dwords = [32 x lo-pair(h2) | 32 x hi-pair(h2)] = 256 B.
__global__ __launch_bounds__(64) void prep_k(const float* __restrict__ shape,
                                             unsigned* __restrict__ ws) {
    const int b = blockIdx.x;       // box 0..29
    const int c = blockIdx.y;       // class 0..49
    const int t = threadIdx.x;      // 0..63
    const int j = t & 31;           // dim pair 0..31
    const bool hiPart = t >= 32;
    const float* src = shape + (size_t)(c * NBOX + b) * 2 * DIM;
    const float a0 = src[2 * j],       a1 = src[2 * j + 1];
    const float e0 = src[DIM + 2 * j], e1 = src[DIM + 2 * j + 1];
    const float v0 = hiPart ? fmaxf(a0, e0) : fminf(a0, e0);
    const float v1 = hiPart ? fmaxf(a1, e1) : fminf(a1, e1);
    h2 h; h.x = (_Float16)v0; h.y = (_Float16)v1;
    ws[(size_t)(c * NBOX + b) * 64 + (hiPart ? 32 : 0) + j] =
        __builtin_bit_cast(unsigned, h);
}

// geom_k: 2 points per thread; box bounds staged once per block in LDS (7.7 KB)
// and read as broadcast h8 (ds_read_b128, no bank conflicts). launch_bounds
// min-waves=5 caps VGPR at 102 so both points stay register-resident (~91 used).
// Cost model: DS ~120 us, VALU ~100 us, overlapping pipes.
__global__ __launch_bounds__(256, 5) void geom_k(const float* __restrict__ data,
                                                 const uint4* __restrict__ boxws,
                                                 float* __restrict__ out) {
    __shared__ uint4 lds4[NBOX * 16];   // 480 x 16 B = 7680 B
    const int c = blockIdx.y;
    const int t = threadIdx.x;

    // Stage this class's boxes into LDS (coalesced 16B loads, 2 passes).
    {
        const uint4* src = boxws + (size_t)c * (NBOX * 16);
        lds4[t] = src[t];
        if (t < NBOX * 16 - 256) lds4[t + 256] = src[t + 256];
    }

    // Load both points (overlaps with staging latency), convert to h8[8].
    const int n = blockIdx.x * 256 + t;
    h8 pA[8], pB[8];
    {
        const float4* va = reinterpret_cast<const float4*>(data + (size_t)n * DIM);
        const float4* vb = reinterpret_cast<const float4*>(data + (size_t)(n + HALF) * DIM);
#pragma unroll
        for (int k = 0; k < 8; ++k) {
            const float4 x0 = va[2 * k], x1 = va[2 * k + 1];
            h8 u;
            u[0] = (_Float16)x0.x; u[1] = (_Float16)x0.y;
            u[2] = (_Float16)x0.z; u[3] = (_Float16)x0.w;
            u[4] = (_Float16)x1.x; u[5] = (_Float16)x1.y;
            u[6] = (_Float16)x1.z; u[7] = (_Float16)x1.w;
            pA[k] = u;
            const float4 y0 = vb[2 * k], y1 = vb[2 * k + 1];
            h8 v;
            v[0] = (_Float16)y0.x; v[1] = (_Float16)y0.y;
            v[2] = (_Float16)y0.z; v[3] = (_Float16)y0.w;
            v[4] = (_Float16)y1.x; v[5] = (_Float16)y1.y;
            v[6] = (_Float16)y1.z; v[7] = (_Float16)y1.w;
            pB[k] = v;
        }
    }

    __syncthreads();

    const h8* lb = reinterpret_cast<const h8*>(lds4);
    float* distOut = out + DIST_OFFSET + (size_t)c * (NBOX * NPTS) + n;
    const h8 zero = (h8)(_Float16)0;

    unsigned townA = 0u, townB = 0u;
#pragma unroll 1
    for (int h = 0; h < NH; ++h) {
        unsigned anyA = 0u, frA = 0u, anyB = 0u, frB = 0u;
#pragma unroll 1
        for (int w = 0; w < NW1; ++w) {
            const int b = h * NW1 + w;
            const h8* bp = lb + b * 16;     // 8 x lo-h8, then 8 x hi-h8
            float sa0 = 0.f, sa1 = 0.f, sb0 = 0.f, sb1 = 0.f;
#pragma unroll
            for (int k = 0; k < 8; ++k) {
                const h8 lo = bp[k];        // ds_read_b128 (broadcast)
                const h8 hi = bp[8 + k];    // ds_read_b128 (broadcast)
                // point A: 8 dims via packed f16, f32 accumulate
                h8 mA = __builtin_elementwise_max(lo - pA[k], pA[k] - hi);
                mA = __builtin_elementwise_max(mA, zero);
                {
                    const h2 q0 = __builtin_shufflevector(mA, mA, 0, 1);
                    const h2 q1 = __builtin_shufflevector(mA, mA, 2, 3);
                    const h2 q2 = __builtin_shufflevector(mA, mA, 4, 5);
                    const h2 q3 = __builtin_shufflevector(mA, mA, 6, 7);
                    sa0 = __builtin_amdgcn_fdot2(q0, q0, sa0, false);
                    sa1 = __builtin_amdgcn_fdot2(q1, q1, sa1, false);
                    sa0 = __builtin_amdgcn_fdot2(q2, q2, sa0, false);
                    sa1 = __builtin_amdgcn_fdot2(q3, q3, sa1, false);
                }
                // point B
                h8 mB = __builtin_elementwise_max(lo - pB[k], pB[k] - hi);
                mB = __builtin_elementwise_max(mB, zero);
                {
                    const h2 q0 = __builtin_shufflevector(mB, mB, 0, 1);
                    const h2 q1 = __builtin_shufflevector(mB, mB, 2, 3);
                    const h2 q2 = __builtin_shufflevector(mB, mB, 4, 5);
                    const h2 q3 = __builtin_shufflevector(mB, mB, 6, 7);
                    sb0 = __builtin_amdgcn_fdot2(q0, q0, sb0, false);
                    sb1 = __builtin_amdgcn_fdot2(q1, q1, sb1, false);
                    sb0 = __builtin_amdgcn_fdot2(q2, q2, sb0, false);
                    sb1 = __builtin_amdgcn_fdot2(q3, q3, sb1, false);
                }
            }
            const float sqA = sa0 + sa1;
            const float sqB = sb0 + sb1;
            distOut[(size_t)b * NPTS] = __builtin_amdgcn_sqrtf(sqA);
            distOut[(size_t)b * NPTS + HALF] = __builtin_amdgcn_sqrtf(sqB);
            const unsigned inA = (sqA == 0.f) ? 1u : 0u;   // inside <=> sq==0
            const unsigned inB = (sqB == 0.f) ? 1u : 0u;
            if (w < NW1 - 1) { anyA |= inA; anyB |= inB; }
            else             { frA = inA;   frB = inB; }
        }
        townA |= (frA & (anyA ^ 1u));
        townB |= (frB & (anyB ^ 1u));
    }
    out[DATA_ELEMS + (size_t)c * NPTS + n] = townA ? 1.0f : 0.0f;
    out[DATA_ELEMS + (size_t)c * NPTS + n + HALF] = townB ? 1.0f : 0.0f;
}

extern "C" void kernel_launch(void* const* d_in, const int* in_sizes, int n_in,
                              void* d_out, int out_size, void* d_ws, size_t ws_size,
                              hipStream_t stream) {
    const float* data  = (const float*)d_in[0];   // [32768,64] f32
    const float* shape = (const float*)d_in[1];   // [50,5,6,2,64] f32
    float* out = (float*)d_out;
    unsigned* ws = (unsigned*)d_ws;               // 50*30*64*4 = 384 KB

    copy_k<<<DATA_ELEMS / 4 / 256, 256, 0, stream>>>(
        (const float4*)data, (float4*)out);

    prep_k<<<dim3(NBOX, NCLS), 64, 0, stream>>>(shape, ws);

    geom_k<<<dim3(HALF / 256, NCLS), 256, 0, stream>>>(
        data, (const uint4*)ws, out);
}